// Round 6
// baseline (480.318 us; speedup 1.0000x reference)
//
#include <hip/hip_runtime.h>

#define NB 64
#define NN 100
#define DL 32

typedef _Float16 f16x8 __attribute__((ext_vector_type(8)));
typedef _Float16 f16x2 __attribute__((ext_vector_type(2)));
typedef float f32x4 __attribute__((ext_vector_type(4)));

static __device__ __forceinline__ float lrelu(float x) { return fmaxf(x, 0.1f * x); }

// Whole network for one batch per block. 1024 threads = 16 waves.
// LDS regions (61392 B static, all 16B-aligned):
//   hS  @0     : f16 [100][34]  6800 B   (h, then h2; stride 34 = odd-word, no dist conflicts)
//   VS  @6800  : f16 [100][72] 14400 B   (V; later t0 f16 [100][64])
//   US  @21200 : f16 [100][64] 12800 B   (U; later h3 f16 [100][32])
//   dwS @34000 : f16 [8][112]   1792 B   (dist window, rebuilt per 8 i's)
//   agg @35792 : f32 [100][64] 25600 B   (f32 for accuracy)
__global__ __launch_bounds__(1024) void k_all(
    const float* __restrict__ x, const float* __restrict__ lw, const float* __restrict__ lb,
    const float* __restrict__ ew0a, const float* __restrict__ eb0a,
    const float* __restrict__ ew1a, const float* __restrict__ eb1a,
    const float* __restrict__ nw0a, const float* __restrict__ nb0a,
    const float* __restrict__ nw1a, const float* __restrict__ nb1a,
    const float* __restrict__ ew0b, const float* __restrict__ eb0b,
    const float* __restrict__ ew1b, const float* __restrict__ eb1b,
    const float* __restrict__ nw0b, const float* __restrict__ nb0b,
    const float* __restrict__ nw1b, const float* __restrict__ nb1b,
    const float* __restrict__ ow, const float* __restrict__ ob,
    float* __restrict__ out) {
    __shared__ __align__(16) unsigned char S[61392];
    _Float16* hS  = (_Float16*)(S);          // stride 34
    _Float16* VS  = (_Float16*)(S + 6800);   // stride 72
    _Float16* t0S = (_Float16*)(S + 6800);   // stride 64 (aliases VS)
    _Float16* US  = (_Float16*)(S + 21200);  // stride 64
    _Float16* h3S = (_Float16*)(S + 21200);  // stride 32 (aliases US)
    _Float16* dwS = (_Float16*)(S + 34000);  // [8][112]
    float*    aggS = (float*)(S + 35792);    // stride 64

    const int b = blockIdx.x;
    const int t = threadIdx.x;
    const int lane = t & 63;
    const int w = t >> 6;                    // 0..15
    const int q = lane >> 4, kk = lane & 15;
    const int kt = w & 3, ig = w >> 2;       // wave owns k-tile kt, i-slots {2ig, 2ig+1}
    const int cb = q * 8;

    // ---- h = x_b @ lin_w + lin_b ----
    for (int o = t; o < NN * DL; o += 1024) {
        float s = lb[o];
#pragma unroll
        for (int cc = 0; cc < DL; ++cc) s += x[b * DL + cc] * lw[cc * (NN * DL) + o];
        hS[(o >> 5) * 34 + (o & 31)] = (_Float16)s;
    }
    __syncthreads();

    for (int step = 0; step < 2; ++step) {
        const float* ew0 = step ? ew0b : ew0a;
        const float* eb0 = step ? eb0b : eb0a;
        const float* ew1 = step ? ew1b : ew1a;
        const float* eb1 = step ? eb1b : eb1a;
        const float* nw0 = step ? nw0b : nw0a;
        const float* nb0 = step ? nb0b : nb0a;
        const float* nw1 = step ? nw1b : nw1a;
        const float* nb1 = step ? nb1b : nb1a;

        // ---- U = h@W0[0:32]+b0, V = h@W0[32:64] ----
        for (int o = t; o < NN * 64; o += 1024) {
            int j = o >> 6, k = o & 63;
            float su = eb0[k], sv = 0.f;
#pragma unroll 8
            for (int c = 0; c < DL; ++c) {
                float hv = (float)hS[j * 34 + c];
                su += hv * ew0[c * 64 + k];
                sv += hv * ew0[(DL + c) * 64 + k];
            }
            US[j * 64 + k] = (_Float16)su;
            VS[j * 72 + k] = (_Float16)sv;
        }

        // per-lane invariants (global reads only; no LDS dependency)
        float wd[16];
#pragma unroll
        for (int e = 0; e < 8; ++e) {
            wd[e] = ew0[64 * 64 + cb + e];
            wd[8 + e] = ew0[64 * 64 + 32 + cb + e];
        }
        f16x8 Bf0, Bf1;
#pragma unroll
        for (int jj = 0; jj < 8; ++jj) {
            Bf0[jj] = (_Float16)ew1[(cb + jj) * 64 + kt * 16 + kk];
            Bf1[jj] = (_Float16)ew1[(32 + cb + jj) * 64 + kt * 16 + kk];
        }
        float b1k = eb1[kt * 16 + kk];
        __syncthreads();

        // ---- edge MLP + aggregation, windows of 8 i ----
        for (int win = 0; win < 13; ++win) {
            int i0 = win * 8;
            int nwi = (i0 + 8 <= NN) ? 8 : (NN - i0);
            // dist window build
            for (int o = t; o < nwi * 112; o += 1024) {
                int iw = o / 112, j = o - iw * 112;
                int i = i0 + iw, jc = j < NN ? j : NN - 1;
                float s = 1e-12f;
#pragma unroll 8
                for (int c = 0; c < DL; c += 2) {
                    f16x2 a2 = *(const f16x2*)&hS[i * 34 + c];
                    f16x2 c2 = *(const f16x2*)&hS[jc * 34 + c];
                    float d0 = (float)a2[0] - (float)c2[0];
                    float d1 = (float)a2[1] - (float)c2[1];
                    s += d0 * d0 + d1 * d1;
                }
                dwS[iw * 112 + j] = (_Float16)sqrtf(s);
            }
            __syncthreads();
            // consume: wave w -> (i = i0 + {2ig,2ig+1}, kt)
            for (int il = 2 * ig; il < 2 * ig + 2; ++il) {
                if (il >= nwi) break;
                int i = i0 + il;
                f16x8 u0h = *(const f16x8*)&US[i * 64 + cb];
                f16x8 u1h = *(const f16x8*)&US[i * 64 + 32 + cb];
                float u0[8], u1[8];
#pragma unroll
                for (int e = 0; e < 8; ++e) { u0[e] = (float)u0h[e]; u1[e] = (float)u1h[e]; }
                f32x4 sacc = {0.f, 0.f, 0.f, 0.f};
#pragma unroll
                for (int jt = 0; jt < 7; ++jt) {
                    int j = jt * 16 + kk;
                    int jc = j < NN ? j : NN - 1;
                    float dj = (float)dwS[il * 112 + j];
                    f16x8 v0 = *(const f16x8*)&VS[jc * 72 + cb];
                    f16x8 v1 = *(const f16x8*)&VS[jc * 72 + 32 + cb];
                    f16x8 A0, A1;
#pragma unroll
                    for (int e = 0; e < 8; ++e) {
                        A0[e] = (_Float16)lrelu(u0[e] + (float)v0[e] + dj * wd[e]);
                        A1[e] = (_Float16)lrelu(u1[e] + (float)v1[e] + dj * wd[8 + e]);
                    }
                    f32x4 a = {0.f, 0.f, 0.f, 0.f};
                    a = __builtin_amdgcn_mfma_f32_16x16x32_f16(A0, Bf0, a, 0, 0, 0);
                    a = __builtin_amdgcn_mfma_f32_16x16x32_f16(A1, Bf1, a, 0, 0, 0);
#pragma unroll
                    for (int r = 0; r < 4; ++r) {
                        int jr = jt * 16 + q * 4 + r;  // C/D row
                        float y = lrelu(a[r] + b1k);
                        sacc[r] += (jr < NN) ? y : 0.f;
                    }
                }
                float s = sacc[0] + sacc[1] + sacc[2] + sacc[3];
                s += __shfl_xor(s, 16);
                s += __shfl_xor(s, 32);
                if (q == 0) aggS[i * 64 + kt * 16 + kk] = s;
            }
            __syncthreads();
        }

        // ---- node MLP layer 0 -> t0 (into VS region; V dead, hS/agg only read) ----
        for (int o = t; o < NN * 64; o += 1024) {
            int i = o >> 6, k = o & 63;
            float s = nb0[k];
#pragma unroll 8
            for (int c = 0; c < DL; ++c) s += (float)hS[i * 34 + c] * nw0[c * 64 + k];
#pragma unroll 8
            for (int c = 0; c < 64; ++c) s += aggS[i * 64 + c] * nw0[(DL + c) * 64 + k];
            t0S[i * 64 + k] = (_Float16)lrelu(s);
        }
        __syncthreads();
        // ---- node MLP layer 1 -> h2 (over hS) or h3 (over US) ----
        for (int o = t; o < NN * DL; o += 1024) {
            int i = o >> 5, c = o & 31;
            float s = nb1[c];
#pragma unroll 8
            for (int cc = 0; cc < 64; ++cc) s += (float)t0S[i * 64 + cc] * nw1[cc * DL + c];
            float hv = lrelu(s);
            if (step == 0) hS[i * 34 + c] = (_Float16)hv;
            else           h3S[i * 32 + c] = (_Float16)hv;
        }
        __syncthreads();
    }

    // ---- out = tanh(h3 @ ow + ob) ----
    for (int o = t; o < NN * 3; o += 1024) {
        int i = o / 3, oo = o - i * 3;
        float s = ob[oo];
#pragma unroll
        for (int c = 0; c < DL; ++c) s += (float)h3S[i * 32 + c] * ow[c * 3 + oo];
        out[b * (NN * 3) + o] = tanhf(s);
    }
}

extern "C" void kernel_launch(void* const* d_in, const int* in_sizes, int n_in,
                              void* d_out, int out_size, void* d_ws, size_t ws_size,
                              hipStream_t stream) {
    const float* x     = (const float*)d_in[0];
    const float* lin_w = (const float*)d_in[1];
    const float* lin_b = (const float*)d_in[2];
    k_all<<<NB, 1024, 0, stream>>>(
        x, lin_w, lin_b,
        (const float*)d_in[3],  (const float*)d_in[4],   // e0_w0, e0_b0
        (const float*)d_in[5],  (const float*)d_in[6],   // e0_w1, e0_b1
        (const float*)d_in[7],  (const float*)d_in[8],   // n0_w0, n0_b0
        (const float*)d_in[9],  (const float*)d_in[10],  // n0_w1, n0_b1
        (const float*)d_in[11], (const float*)d_in[12],  // e1_w0, e1_b0
        (const float*)d_in[13], (const float*)d_in[14],  // e1_w1, e1_b1
        (const float*)d_in[15], (const float*)d_in[16],  // n1_w0, n1_b0
        (const float*)d_in[17], (const float*)d_in[18],  // n1_w1, n1_b1
        (const float*)d_in[19], (const float*)d_in[20],  // out_w, out_b
        (float*)d_out);
}

// Round 8
// 210.173 us; speedup vs baseline: 2.2853x; 2.2853x over previous
//
#include <hip/hip_runtime.h>

#define NB 64
#define NN 100
#define DL 32
#define BN (NB * NN)  // 6400

typedef _Float16 f16x8 __attribute__((ext_vector_type(8)));
typedef float f32x4 __attribute__((ext_vector_type(4)));

static __device__ __forceinline__ float lrelu(float x) { return fmaxf(x, 0.1f * x); }

// Fused prep: h = x@lin_w+lin_b (f32), Uh/Vh f16 for step 0, W1 B-fragment swizzle
// (f16) + dist-row wdh for both steps.
// Blocks 0..1599: 4 (b,n) rows each. Blocks 1600..1601: PW/wdh for step 0/1.
__global__ __launch_bounds__(256) void k_pre(
    const float* __restrict__ x, const float* __restrict__ lw, const float* __restrict__ lb,
    const float* __restrict__ ew0a, const float* __restrict__ eb0a,
    const float* __restrict__ ew0b,
    const float* __restrict__ w1a, const float* __restrict__ w1b,
    float* __restrict__ h, _Float16* __restrict__ Uh, _Float16* __restrict__ Vh,
    _Float16* __restrict__ PW) {
    int blk = blockIdx.x;
    int t = threadIdx.x;
    if (blk >= 1600) {  // PW[step][kt][hf][lane][jj] + wdh[step][64] at PW+8192
        int step = blk - 1600;
        const float* w1 = step ? w1b : w1a;
        const float* ew0 = step ? ew0b : ew0a;
        _Float16* dst = PW + step * 4096;
#pragma unroll
        for (int u = 0; u < 16; ++u) {
            int idx = t * 16 + u;
            int jj = idx & 7, lane = (idx >> 3) & 63, hf = (idx >> 9) & 1, kt = idx >> 10;
            int c = hf * 32 + (lane >> 4) * 8 + jj;
            int k = kt * 16 + (lane & 15);
            dst[idx] = (_Float16)w1[c * 64 + k];
        }
        if (t < 64) PW[8192 + step * 64 + t] = (_Float16)ew0[64 * 64 + t];
        return;
    }
    __shared__ float xs[DL];
    __shared__ float hs[4][DL];
    int row0 = blk * 4;
    int b = row0 / NN;  // 4-row group never crosses a batch boundary (100 % 4 == 0)
    if (t < DL) xs[t] = x[b * DL + t];
    __syncthreads();
    if (t < 128) {
        int ni = t >> 5, c = t & 31;
        int n = (row0 + ni) % NN;
        float s = lb[n * DL + c];
#pragma unroll
        for (int cc = 0; cc < DL; ++cc) s += xs[cc] * lw[cc * 3200 + n * DL + c];
        hs[ni][c] = s;
        h[(row0 + ni) * DL + c] = s;
    }
    __syncthreads();
#pragma unroll
    for (int r = 0; r < 2; ++r) {
        int o = r * 256 + t;  // 0..511 : 4 rows x (64 U + 64 V)
        int ni = o >> 7, kw = o & 127;
        int which = kw >> 6, k = kw & 63;
        const float* wp = ew0a + (which ? DL * 64 : 0) + k;
        float s = which ? 0.f : eb0a[k];
#pragma unroll
        for (int c = 0; c < DL; ++c) s += hs[ni][c] * wp[c * 64];
        (which ? Vh : Uh)[(row0 + ni) * 64 + k] = (_Float16)s;
    }
}

// Block = 2 i's x 2 k-half waves (grid 3200, 256 thr). Each wave is independent in
// the edge loop: A-fragments built in-register in packed f16 (no LDS P, no barriers).
// wdh passed as its OWN pointer (R7 bug: reading it relative to the shifted
// fragment base read 0xAA poison for step 1).
template <int FINAL>
__global__ __launch_bounds__(256, 2) void k_edge_node(
    const float* __restrict__ h, const _Float16* __restrict__ Uh,
    const _Float16* __restrict__ Vh, const _Float16* __restrict__ PW,
    const _Float16* __restrict__ wdh,
    const float* __restrict__ b1,
    const float* __restrict__ w0n, const float* __restrict__ b0n,
    const float* __restrict__ w1n, const float* __restrict__ b1n,
    const float* __restrict__ wA, const float* __restrict__ bA,
    float* __restrict__ hout, _Float16* __restrict__ Uo, _Float16* __restrict__ Vo,
    float* __restrict__ out) {
    __shared__ float dist[2][112];
    __shared__ float hiS[2][DL];
    __shared__ float aggS[2][64];
    __shared__ float t0S[2][64];
    __shared__ float h2S[2][DL];

    const int i0 = blockIdx.x * 2;
    const int b = i0 / NN;  // pair never crosses batch (100 % 2 == 0)
    const int t = threadIdx.x;
    const int w = t >> 6, lane = t & 63, q = lane >> 4, kk = lane & 15;
    const int il = w >> 1;        // which i of the pair this wave works on
    const int k0 = (w & 1) * 2;   // first of the 2 k-tiles this wave owns
    const int cb = q * 8;

    // dist window: 224 entries, 1 thread each
    if (t < 224) {
        int dl = t / 112, j = t - dl * 112;
        int jc = j < NN ? j : NN - 1;
        const float4* hi4 = (const float4*)(h + (i0 + dl) * DL);
        const float4* hj4 = (const float4*)(h + (b * NN + jc) * DL);
        float s = 1e-12f;
#pragma unroll
        for (int r = 0; r < 8; ++r) {
            float4 a = hi4[r], c = hj4[r];
            float d0 = a.x - c.x, d1 = a.y - c.y, d2 = a.z - c.z, d3 = a.w - c.w;
            s += d0 * d0 + d1 * d1 + d2 * d2 + d3 * d3;
        }
        dist[dl][j] = sqrtf(s);
    }
    if (t < 64) hiS[t >> 5][t & 31] = h[(i0 + (t >> 5)) * DL + (t & 31)];

    // per-lane invariants (f16): U_i(+b0), dist-row of W0, B-fragments, b1
    const int i = i0 + il;
    f16x8 u0 = *(const f16x8*)&Uh[i * 64 + cb];
    f16x8 u1 = *(const f16x8*)&Uh[i * 64 + 32 + cb];
    f16x8 wd0 = *(const f16x8*)&wdh[cb];
    f16x8 wd1 = *(const f16x8*)&wdh[32 + cb];
    f16x8 Bf[2][2];
#pragma unroll
    for (int kp = 0; kp < 2; ++kp)
#pragma unroll
        for (int hf = 0; hf < 2; ++hf)
            Bf[kp][hf] = *(const f16x8*)&PW[(((k0 + kp) * 2 + hf) * 64 + lane) * 8];
    float b1k[2] = {b1[k0 * 16 + kk], b1[(k0 + 1) * 16 + kk]};

    f32x4 sacc[2];
    sacc[0] = (f32x4){0.f, 0.f, 0.f, 0.f};
    sacc[1] = (f32x4){0.f, 0.f, 0.f, 0.f};
    __syncthreads();

    const _Float16* vbase = Vh + (size_t)(b * NN) * 64;
#pragma unroll
    for (int jt = 0; jt < 7; ++jt) {
        int j = jt * 16 + kk;  // A row m = lane&15
        int jc = j < NN ? j : NN - 1;
        _Float16 dh = (_Float16)dist[il][j];
        f16x8 v0 = *(const f16x8*)&vbase[jc * 64 + cb];
        f16x8 v1 = *(const f16x8*)&vbase[jc * 64 + 32 + cb];
        f16x8 s0 = u0 + v0 + wd0 * dh;  // v_pk_add / v_pk_fma
        f16x8 s1 = u1 + v1 + wd1 * dh;
        f16x8 A0 = __builtin_elementwise_max(s0, s0 * (_Float16)0.1f);
        f16x8 A1 = __builtin_elementwise_max(s1, s1 * (_Float16)0.1f);
#pragma unroll
        for (int kp = 0; kp < 2; ++kp) {
            f32x4 a = {0.f, 0.f, 0.f, 0.f};
            a = __builtin_amdgcn_mfma_f32_16x16x32_f16(A0, Bf[kp][0], a, 0, 0, 0);
            a = __builtin_amdgcn_mfma_f32_16x16x32_f16(A1, Bf[kp][1], a, 0, 0, 0);
#pragma unroll
            for (int r = 0; r < 4; ++r) {
                int jr = jt * 16 + q * 4 + r;  // C/D row
                float y = lrelu(a[r] + b1k[kp]);
                sacc[kp][r] += (jr < NN) ? y : 0.f;
            }
        }
    }

#pragma unroll
    for (int kp = 0; kp < 2; ++kp) {
        float s = sacc[kp][0] + sacc[kp][1] + sacc[kp][2] + sacc[kp][3];
        s += __shfl_xor(s, 16);
        s += __shfl_xor(s, 32);
        if (q == 0) aggS[il][(k0 + kp) * 16 + kk] = s;
    }
    __syncthreads();

    // node MLP layer 0: 128 threads -> 2 i x 64 outputs
    if (t < 128) {
        int dl = t >> 6, k = t & 63;
        float s = b0n[k];
#pragma unroll 8
        for (int c = 0; c < DL; ++c) s += hiS[dl][c] * w0n[c * 64 + k];
#pragma unroll 8
        for (int c = 0; c < 64; ++c) s += aggS[dl][c] * w0n[(DL + c) * 64 + k];
        t0S[dl][k] = lrelu(s);
    }
    __syncthreads();
    if (t < 64) {  // node MLP layer 1: 2 i x 32
        int dl = t >> 5, c = t & 31;
        float s = b1n[c];
#pragma unroll 8
        for (int cc = 0; cc < 64; ++cc) s += t0S[dl][cc] * w1n[cc * DL + c];
        float hv = lrelu(s);
        h2S[dl][c] = hv;
        if (!FINAL) hout[(i0 + dl) * DL + c] = hv;
    }
    __syncthreads();
    if (FINAL) {
        if (t < 6) {
            int dl = t / 3, o = t - dl * 3;
            float s = bA[o];
#pragma unroll
            for (int c = 0; c < DL; ++c) s += h2S[dl][c] * wA[c * 3 + o];
            out[(i0 + dl) * 3 + o] = tanhf(s);
        }
    } else {  // next step's Uh/Vh: 256 threads = 2 i x (64 U + 64 V)
        int dl = t >> 7, kw = t & 127;
        int which = kw >> 6, k = kw & 63;
        const float* wp = wA + (which ? DL * 64 : 0) + k;
        float s = which ? 0.f : bA[k];
#pragma unroll
        for (int c = 0; c < DL; ++c) s += h2S[dl][c] * wp[c * 64];
        (which ? Vo : Uo)[(i0 + dl) * 64 + k] = (_Float16)s;
    }
}

extern "C" void kernel_launch(void* const* d_in, const int* in_sizes, int n_in,
                              void* d_out, int out_size, void* d_ws, size_t ws_size,
                              hipStream_t stream) {
    const float* x     = (const float*)d_in[0];
    const float* lin_w = (const float*)d_in[1];
    const float* lin_b = (const float*)d_in[2];
    const float* ew0[2] = {(const float*)d_in[3],  (const float*)d_in[11]};
    const float* eb0[2] = {(const float*)d_in[4],  (const float*)d_in[12]};
    const float* ew1[2] = {(const float*)d_in[5],  (const float*)d_in[13]};
    const float* eb1[2] = {(const float*)d_in[6],  (const float*)d_in[14]};
    const float* nw0[2] = {(const float*)d_in[7],  (const float*)d_in[15]};
    const float* nb0[2] = {(const float*)d_in[8],  (const float*)d_in[16]};
    const float* nw1[2] = {(const float*)d_in[9],  (const float*)d_in[17]};
    const float* nb1[2] = {(const float*)d_in[10], (const float*)d_in[18]};
    const float* ow = (const float*)d_in[19];
    const float* ob = (const float*)d_in[20];
    float* out = (float*)d_out;

    float* h   = (float*)d_ws;                    // 6400 x 32 f32
    float* h2  = h + 204800;                      // 6400 x 32 f32
    _Float16* Uh  = (_Float16*)(h2 + 204800);     // 6400 x 64 f16
    _Float16* Vh  = Uh + 409600;
    _Float16* Uh2 = Vh + 409600;
    _Float16* Vh2 = Uh2 + 409600;
    _Float16* PW  = Vh2 + 409600;                 // 2x4096 B-frags + 2x64 wdh

    k_pre<<<1602, 256, 0, stream>>>(x, lin_w, lin_b, ew0[0], eb0[0], ew0[1],
                                    ew1[0], ew1[1], h, Uh, Vh, PW);
    k_edge_node<0><<<BN / 2, 256, 0, stream>>>(h, Uh, Vh, PW, PW + 8192, eb1[0],
                                               nw0[0], nb0[0], nw1[0], nb1[0],
                                               ew0[1], eb0[1], h2, Uh2, Vh2, nullptr);
    k_edge_node<1><<<BN / 2, 256, 0, stream>>>(h2, Uh2, Vh2, PW + 4096, PW + 8256,
                                               eb1[1],
                                               nw0[1], nb0[1], nw1[1], nb1[1],
                                               ow, ob, nullptr, nullptr, nullptr, out);
}